// Round 3
// baseline (137.884 us; speedup 1.0000x reference)
//
#include <hip/hip_runtime.h>
#include <hip/hip_bf16.h>

#define NROWS 8192
#define KDIM  512
#define NT    64                 // 8192/128 tiles per dim
#define NBLK  (NT*(NT+1)/2)      // upper-triangle tile pairs = 2080
#define BK    64
#define NITER (KDIM/BK)          // 8

typedef __attribute__((ext_vector_type(16))) float f32x16;

__device__ __forceinline__ void async_copy16(const void* g, void* l) {
    __builtin_amdgcn_global_load_lds((const __attribute__((address_space(1))) void*)g,
                                     (__attribute__((address_space(3))) void*)l,
                                     16, 0, 0);
}

// Raw barrier/waitcnt: keep prefetch loads in flight across the barrier
// (HIP __syncthreads would emit s_waitcnt vmcnt(0) and drain the pipeline).
#define RAW_BARRIER() asm volatile("s_barrier" ::: "memory")
#define WAITVM(n)     asm volatile("s_waitcnt vmcnt(" #n ")" ::: "memory")

// z (fp32) -> fp8 e4m3 into workspace, sq[i] = ||z_i||^2 in fp32, zero acc+cnt.
__global__ __launch_bounds__(256) void prep_kernel(const float* __restrict__ z,
                                                   unsigned char* __restrict__ zb,
                                                   float* __restrict__ sq,
                                                   float* __restrict__ acc,
                                                   unsigned* __restrict__ cnt) {
    int wave = threadIdx.x >> 6, lane = threadIdx.x & 63;
    int row = blockIdx.x * 4 + wave;
    const float* zr = z + (size_t)row * KDIM + lane * 8;
    float4 v0 = *(const float4*)zr;
    float4 v1 = *(const float4*)(zr + 4);
    float vals[8] = {v0.x, v0.y, v0.z, v0.w, v1.x, v1.y, v1.z, v1.w};
    float s = 0.f;
#pragma unroll
    for (int i = 0; i < 8; ++i) s += vals[i] * vals[i];
    int lo = __builtin_amdgcn_cvt_pk_fp8_f32(vals[0], vals[1], 0, false);
    lo     = __builtin_amdgcn_cvt_pk_fp8_f32(vals[2], vals[3], lo, true);
    int hi = __builtin_amdgcn_cvt_pk_fp8_f32(vals[4], vals[5], 0, false);
    hi     = __builtin_amdgcn_cvt_pk_fp8_f32(vals[6], vals[7], hi, true);
    int2 pk; pk.x = lo; pk.y = hi;
    *(int2*)(zb + (size_t)row * KDIM + lane * 8) = pk;
#pragma unroll
    for (int off = 32; off; off >>= 1) s += __shfl_down(s, off);
    if (lane == 0) sq[row] = s;
    if (blockIdx.x == 0 && threadIdx.x == 0) { acc[0] = 0.f; cnt[0] = 0u; }
}

__global__ __launch_bounds__(256) void gram_kernel(const unsigned char* __restrict__ zb,
                                                   const float* __restrict__ sq,
                                                   float* __restrict__ acc,
                                                   unsigned* __restrict__ cnt,
                                                   float* __restrict__ out) {
    // double-buffered: 2 x (8 KB A + 8 KB B) = 32 KB -> 4 blocks/CU
    __shared__ __align__(16) unsigned char Ash[2][128 * BK];
    __shared__ __align__(16) unsigned char Bsh[2][128 * BK];

    int tid = threadIdx.x;
    int wave = tid >> 6, lane = tid & 63;
    int ln31 = lane & 31, khalf = lane >> 5;
    int wm = wave >> 1, wn = wave & 1;

    // linear block id -> (bi, bj), bi <= bj
    int rem = blockIdx.x, bi = 0;
    while (rem >= NT - bi) { rem -= NT - bi; ++bi; }
    int bj = bi + rem;

    const unsigned char* Ag = zb + (size_t)(bi * 128) * KDIM;
    const unsigned char* Bg = zb + (size_t)(bj * 128) * KDIM;

    // staging source addresses (k0-independent parts): chunk c -> (row, cc)
    int cA = tid, rowA = cA >> 2, ccA = cA & 3;
    int scA = ccA ^ ((rowA >> 1) & 3);
    int cB = 256 + tid, rowB = cB >> 2, ccB = cB & 3;
    int scB = ccB ^ ((rowB >> 1) & 3);

    f32x16 accf[2][2];
#pragma unroll
    for (int mi = 0; mi < 2; ++mi)
#pragma unroll
        for (int ni = 0; ni < 2; ++ni)
#pragma unroll
            for (int r = 0; r < 16; ++r) accf[mi][ni][r] = 0.f;

    int key = (ln31 >> 1) & 3;          // bank swizzle key (row-derived)
    const unsigned char* aB0 = Ash[0] + (wm * 64 + ln31) * BK + khalf * 8;
    const unsigned char* bB0 = Bsh[0] + (wn * 64 + ln31) * BK + khalf * 8;

    // ---- stage(b, k0): 4 async 16B copies per thread (A0,B0,A1,B1) ----
#define STAGE(b, k0)                                                              \
    do {                                                                          \
        async_copy16(Ag + (size_t)rowA * KDIM + (k0) + scA * 16, &Ash[b][cA * 16]); \
        async_copy16(Bg + (size_t)rowA * KDIM + (k0) + scA * 16, &Bsh[b][cA * 16]); \
        async_copy16(Ag + (size_t)rowB * KDIM + (k0) + scB * 16, &Ash[b][cB * 16]); \
        async_copy16(Bg + (size_t)rowB * KDIM + (k0) + scB * 16, &Bsh[b][cB * 16]); \
    } while (0)

#define COMPUTE(b)                                                                \
    do {                                                                          \
        const unsigned char* aB = aB0 + (b) * 128 * BK;                           \
        const unsigned char* bB = bB0 + (b) * 128 * BK;                           \
        _Pragma("unroll")                                                         \
        for (int s = 0; s < BK / 16; ++s) {                                       \
            int off = ((s ^ key) * 16);                                           \
            long a0 = *(const long*)(aB + off);                                   \
            long a1 = *(const long*)(aB + off + 32 * BK);                         \
            long b0 = *(const long*)(bB + off);                                   \
            long b1 = *(const long*)(bB + off + 32 * BK);                         \
            accf[0][0] = __builtin_amdgcn_mfma_f32_32x32x16_fp8_fp8(a0, b0, accf[0][0], 0, 0, 0); \
            accf[0][1] = __builtin_amdgcn_mfma_f32_32x32x16_fp8_fp8(a0, b1, accf[0][1], 0, 0, 0); \
            accf[1][0] = __builtin_amdgcn_mfma_f32_32x32x16_fp8_fp8(a1, b0, accf[1][0], 0, 0, 0); \
            accf[1][1] = __builtin_amdgcn_mfma_f32_32x32x16_fp8_fp8(a1, b1, accf[1][1], 0, 0, 0); \
        }                                                                         \
    } while (0)

    STAGE(0, 0);
#pragma unroll
    for (int i = 0; i < NITER - 1; ++i) {
        int b = i & 1;
        RAW_BARRIER();            // all readers of buffer b^1 are done
        STAGE(b ^ 1, (i + 1) * BK);
        WAITVM(4);                // my iter-i loads have landed in LDS
        RAW_BARRIER();            // everyone's iter-i loads have landed
        COMPUTE(b);
    }
    RAW_BARRIER();
    WAITVM(0);
    RAW_BARRIER();
    COMPUTE((NITER - 1) & 1);

    // ---- fused epilogue: exp(-D/tau) for gi<gj ----
    int rowBase = bi * 128 + wm * 64;
    int colBase = bj * 128 + wn * 64;
    float sqj[2] = { sq[colBase + ln31], sq[colBase + 32 + ln31] };

    float local = 0.f;
#pragma unroll
    for (int mi = 0; mi < 2; ++mi) {
#pragma unroll
        for (int reg = 0; reg < 16; ++reg) {
            int rowf = (reg & 3) + 8 * (reg >> 2) + 4 * khalf;   // C/D row (m74/m101)
            int gi = rowBase + mi * 32 + rowf;
            float sqi = sq[gi];
#pragma unroll
            for (int ni = 0; ni < 2; ++ni) {
                int gj = colBase + ni * 32 + ln31;               // C/D col = lane&31
                float d = sqi + sqj[ni] - 2.f * accf[mi][ni][reg];
                d = fmaxf(d, 0.f);
                float e = __expf(d * (-1.f / 100.f));
                local += (gi < gj) ? e : 0.f;
            }
        }
    }

#pragma unroll
    for (int off = 32; off; off >>= 1) local += __shfl_down(local, off);
    __shared__ float wsum[4];
    if (lane == 0) wsum[wave] = local;
    __syncthreads();
    if (tid == 0) {
        atomicAdd(acc, wsum[0] + wsum[1] + wsum[2] + wsum[3]);
        __threadfence();
        unsigned t = atomicAdd(cnt, 1u);
        if (t == NBLK - 1) {
            float total = 2.f * atomicAdd(acc, 0.f);
            out[0] = logf(total / ((float)NROWS * (float)(NROWS - 1)));
        }
    }
}

extern "C" void kernel_launch(void* const* d_in, const int* in_sizes, int n_in,
                              void* d_out, int out_size, void* d_ws, size_t ws_size,
                              hipStream_t stream) {
    const float* z = (const float*)d_in[0];
    float* out = (float*)d_out;
    unsigned char* zb = (unsigned char*)d_ws;                     // 4 MB fp8
    float* sq = (float*)((char*)d_ws + (size_t)NROWS * KDIM);     // 32 KB
    float* acc = sq + NROWS;                                      // 4 B
    unsigned* cnt = (unsigned*)(acc + 1);                         // 4 B

    prep_kernel<<<NROWS / 4, 256, 0, stream>>>(z, zb, sq, acc, cnt);
    gram_kernel<<<NBLK, 256, 0, stream>>>(zb, sq, acc, cnt, out);
}

// Round 4
// 132.895 us; speedup vs baseline: 1.0375x; 1.0375x over previous
//
#include <hip/hip_runtime.h>
#include <hip/hip_bf16.h>

#define NROWS 8192
#define KDIM  512
#define NT    64                 // 8192/128 tiles per dim
#define NBLK  (NT*(NT+1)/2)      // upper-triangle tile pairs = 2080
#define SCL1  0x7F7F7F7F         // E8M0 scale bytes = 2^0 = 1.0

typedef __attribute__((ext_vector_type(16))) float f32x16;
typedef __attribute__((ext_vector_type(4))) int i32x4;
typedef __attribute__((ext_vector_type(8))) int i32x8;

__device__ __forceinline__ void async_copy16(const void* g, void* l) {
    __builtin_amdgcn_global_load_lds((const __attribute__((address_space(1))) void*)g,
                                     (__attribute__((address_space(3))) void*)l,
                                     16, 0, 0);
}

// two ds_read_b128 -> one 8xi32 MFMA operand (k 0..15 from p0, k 16..31 from p1)
__device__ __forceinline__ i32x8 ld_frag(const unsigned char* p0, const unsigned char* p1) {
    i32x4 lo = *(const i32x4*)p0;
    i32x4 hi = *(const i32x4*)p1;
    i32x8 r;
    r[0] = lo[0]; r[1] = lo[1]; r[2] = lo[2]; r[3] = lo[3];
    r[4] = hi[0]; r[5] = hi[1]; r[6] = hi[2]; r[7] = hi[3];
    return r;
}

// z (fp32) -> fp8 e4m3 into workspace, sq[i] = ||z_i||^2 in fp32, zero acc+cnt.
__global__ __launch_bounds__(256) void prep_kernel(const float* __restrict__ z,
                                                   unsigned char* __restrict__ zb,
                                                   float* __restrict__ sq,
                                                   float* __restrict__ acc,
                                                   unsigned* __restrict__ cnt) {
    int wave = threadIdx.x >> 6, lane = threadIdx.x & 63;
    int row = blockIdx.x * 4 + wave;
    const float* zr = z + (size_t)row * KDIM + lane * 8;
    float4 v0 = *(const float4*)zr;
    float4 v1 = *(const float4*)(zr + 4);
    float vals[8] = {v0.x, v0.y, v0.z, v0.w, v1.x, v1.y, v1.z, v1.w};
    float s = 0.f;
#pragma unroll
    for (int i = 0; i < 8; ++i) s += vals[i] * vals[i];
    int lo = __builtin_amdgcn_cvt_pk_fp8_f32(vals[0], vals[1], 0, false);
    lo     = __builtin_amdgcn_cvt_pk_fp8_f32(vals[2], vals[3], lo, true);
    int hi = __builtin_amdgcn_cvt_pk_fp8_f32(vals[4], vals[5], 0, false);
    hi     = __builtin_amdgcn_cvt_pk_fp8_f32(vals[6], vals[7], hi, true);
    int2 pk; pk.x = lo; pk.y = hi;
    *(int2*)(zb + (size_t)row * KDIM + lane * 8) = pk;
#pragma unroll
    for (int off = 32; off; off >>= 1) s += __shfl_down(s, off);
    if (lane == 0) sq[row] = s;
    if (blockIdx.x == 0 && threadIdx.x == 0) { acc[0] = 0.f; cnt[0] = 0u; }
}

// One 128x128 Gram tile per block, FULL-K in LDS (A 64KB + B 64KB), single
// barrier, MX-scaled fp8 MFMA K=64, fused exp epilogue, last-block log.
// LDS layout (per tile): addr = kb*8192 + row*64 + (c ^ ((row>>1)&3))*16
//   kb = k-block of 64 fp8, c = 16B granule within k-block (0..3).
// This is conflict-free for both the coalesced staging and the b128 frag reads.
__global__ __launch_bounds__(256) void gram_kernel(const unsigned char* __restrict__ zb,
                                                   const float* __restrict__ sq,
                                                   float* __restrict__ acc,
                                                   unsigned* __restrict__ cnt,
                                                   float* __restrict__ out) {
    __shared__ __align__(16) unsigned char Ash[128 * 512];   // 64 KB
    __shared__ __align__(16) unsigned char Bsh[128 * 512];   // 64 KB
    __shared__ float wsum[4];

    int tid = threadIdx.x;
    int wave = tid >> 6, lane = tid & 63;
    int ln31 = lane & 31, kh = lane >> 5;
    int wm = wave >> 1, wn = wave & 1;

    // linear block id -> (bi, bj), bi <= bj
    int rem = blockIdx.x, bi = 0;
    while (rem >= NT - bi) { rem -= NT - bi; ++bi; }
    int bj = bi + rem;
    bool diag = (bi == bj);

    const unsigned char* Ag = zb + (size_t)(bi * 128) * KDIM;
    const unsigned char* Bg = zb + (size_t)(bj * 128) * KDIM;

    // ---- stage full tiles: 16 (+16) x 16B async copies per thread ----
#pragma unroll
    for (int j = 0; j < 16; ++j) {
        int L = j * 256 + tid;                 // linear 16B-granule index
        int kb = L >> 9, r2 = L & 511;
        int row = r2 >> 2, cp = r2 & 3;
        int c = cp ^ ((row >> 1) & 3);         // global granule (un-swizzle)
        size_t goff = (size_t)row * KDIM + kb * 64 + c * 16;
        async_copy16(Ag + goff, Ash + L * 16);
        if (!diag) async_copy16(Bg + goff, Bsh + L * 16);
    }
    __syncthreads();
    const unsigned char* Bs = diag ? Ash : Bsh;

    // ---- fragment LDS offsets (k-block-invariant parts) ----
    int rowA[2] = { wm * 64 + ln31, wm * 64 + 32 + ln31 };
    int colB[2] = { wn * 64 + ln31, wn * 64 + 32 + ln31 };
    int aOff0[2], aOff1[2], bOff0[2], bOff1[2];
#pragma unroll
    for (int i = 0; i < 2; ++i) {
        int ka = (rowA[i] >> 1) & 3, kb_ = (colB[i] >> 1) & 3;
        aOff0[i] = rowA[i] * 64 + (((2 * kh)     ^ ka) * 16);
        aOff1[i] = rowA[i] * 64 + (((2 * kh + 1) ^ ka) * 16);
        bOff0[i] = colB[i] * 64 + (((2 * kh)     ^ kb_) * 16);
        bOff1[i] = colB[i] * 64 + (((2 * kh + 1) ^ kb_) * 16);
    }

    f32x16 accf[2][2];
#pragma unroll
    for (int mi = 0; mi < 2; ++mi)
#pragma unroll
        for (int ni = 0; ni < 2; ++ni)
#pragma unroll
            for (int r = 0; r < 16; ++r) accf[mi][ni][r] = 0.f;

    // ---- uninterrupted MFMA loop over 8 k-blocks of 64 ----
#pragma unroll
    for (int kb = 0; kb < 8; ++kb) {
        const unsigned char* aBase = Ash + kb * 8192;
        const unsigned char* bBase = Bs  + kb * 8192;
        i32x8 a0 = ld_frag(aBase + aOff0[0], aBase + aOff1[0]);
        i32x8 a1 = ld_frag(aBase + aOff0[1], aBase + aOff1[1]);
        i32x8 b0 = ld_frag(bBase + bOff0[0], bBase + bOff1[0]);
        i32x8 b1 = ld_frag(bBase + bOff0[1], bBase + bOff1[1]);
        accf[0][0] = __builtin_amdgcn_mfma_scale_f32_32x32x64_f8f6f4(a0, b0, accf[0][0], 0, 0, 0, SCL1, 0, SCL1);
        accf[0][1] = __builtin_amdgcn_mfma_scale_f32_32x32x64_f8f6f4(a0, b1, accf[0][1], 0, 0, 0, SCL1, 0, SCL1);
        accf[1][0] = __builtin_amdgcn_mfma_scale_f32_32x32x64_f8f6f4(a1, b0, accf[1][0], 0, 0, 0, SCL1, 0, SCL1);
        accf[1][1] = __builtin_amdgcn_mfma_scale_f32_32x32x64_f8f6f4(a1, b1, accf[1][1], 0, 0, 0, SCL1, 0, SCL1);
    }

    // ---- fused epilogue: exp(-D/tau) for gi<gj ----
    int rowBase = bi * 128 + wm * 64;
    int colBase = bj * 128 + wn * 64;
    float sqj[2] = { sq[colBase + ln31], sq[colBase + 32 + ln31] };

    float local = 0.f;
#pragma unroll
    for (int mi = 0; mi < 2; ++mi) {
#pragma unroll
        for (int reg = 0; reg < 16; ++reg) {
            int rowf = (reg & 3) + 8 * (reg >> 2) + 4 * kh;   // 32x32 C/D row (m74/m101)
            int gi = rowBase + mi * 32 + rowf;
            float sqi = sq[gi];
#pragma unroll
            for (int ni = 0; ni < 2; ++ni) {
                int gj = colBase + ni * 32 + ln31;            // C/D col = lane&31
                float d = sqi + sqj[ni] - 2.f * accf[mi][ni][reg];
                d = fmaxf(d, 0.f);
                float e = __expf(d * (-1.f / 100.f));
                local += (gi < gj) ? e : 0.f;
            }
        }
    }

#pragma unroll
    for (int off = 32; off; off >>= 1) local += __shfl_down(local, off);
    if (lane == 0) wsum[wave] = local;
    __syncthreads();
    if (tid == 0) {
        atomicAdd(acc, wsum[0] + wsum[1] + wsum[2] + wsum[3]);
        __threadfence();
        unsigned t = atomicAdd(cnt, 1u);
        if (t == NBLK - 1) {
            float total = 2.f * atomicAdd(acc, 0.f);
            out[0] = logf(total / ((float)NROWS * (float)(NROWS - 1)));
        }
    }
}

extern "C" void kernel_launch(void* const* d_in, const int* in_sizes, int n_in,
                              void* d_out, int out_size, void* d_ws, size_t ws_size,
                              hipStream_t stream) {
    const float* z = (const float*)d_in[0];
    float* out = (float*)d_out;
    unsigned char* zb = (unsigned char*)d_ws;                     // 4 MB fp8
    float* sq = (float*)((char*)d_ws + (size_t)NROWS * KDIM);     // 32 KB
    float* acc = sq + NROWS;                                      // 4 B
    unsigned* cnt = (unsigned*)(acc + 1);                         // 4 B

    prep_kernel<<<NROWS / 4, 256, 0, stream>>>(z, zb, sq, acc, cnt);
    gram_kernel<<<NBLK, 256, 0, stream>>>(zb, sq, acc, cnt, out);
}